// Round 15
// baseline (158.108 us; speedup 1.0000x reference)
//
#include <hip/hip_runtime.h>
#include <math.h>

#define Bn 4
#define Nn 4096
#define Kn 16
#define Cn 128
#define HIDn 64

// ws layout (float offsets)
#define OFF_WQKVBF 0          // 49152 bf16 = 24576 f
#define OFF_WM1BF  24576      // 65536 bf16 = 32768 f
#define OFF_WM2BF  57344      // 65536 bf16 = 32768 f
#define OFF_W2BFG  90112      // 8192 bf16 = 4096 f
#define OFF_QNBF   95232      // 1048576 f
#define OFF_KMBF   1143808    // 1048576 f
#define OFF_VMBF   2192384    // 1048576 f
#define OFF_KVT32  3240960    // B*K*C*C f32 (atomic target, [b,k,d,c])
#define OFF_KVTBF  4289536    // 524288 f   (pre-k2b: jn32[B*K*N] int32 = 262144 f)
#define OFF_AGG0   4813824    // 2097152 f
#define OFF_AGG1   6910976    // 2097152 f  (pre-k3: feat bf16[B*K*N*16] = 2097152 f)
#define OFF_FLAG   9008128    // 1 int

typedef short bf16x8 __attribute__((ext_vector_type(8)));
typedef float f32x4 __attribute__((ext_vector_type(4)));

__device__ inline unsigned short f2bf(float f) {
  union { float f; unsigned u; } v; v.f = f;
  unsigned r = v.u + 0x7fffu + ((v.u >> 16) & 1u);
  return (unsigned short)(r >> 16);
}
__device__ inline float b2f(unsigned short s) {
  union { unsigned u; float f; } v; v.u = ((unsigned)s) << 16; return v.f;
}

// ---------------- K0: weight bf16 casts + idx dtype probe ----------------
__global__ void k0_prep(const float* __restrict__ Wqkv,
                        const float* __restrict__ Wm1, const float* __restrict__ Wm2,
                        const float* __restrict__ W2,
                        const int* __restrict__ idx_raw, float* ws) {
  if (blockIdx.x == 0 && threadIdx.x == 0) {
    int any = 0;
    for (int i = 0; i < 64; ++i) any |= idx_raw[2 * i + 1];
    ((int*)(ws + OFF_FLAG))[0] = (any == 0) ? 1 : 0;   // 1 => idx is int64
  }
  int t = blockIdx.x * 256 + threadIdx.x;
  if (t < 49152) { ((unsigned short*)(ws + OFF_WQKVBF))[t] = f2bf(Wqkv[t]); return; }
  t -= 49152;
  if (t < 65536) { ((unsigned short*)(ws + OFF_WM1BF))[t] = f2bf(Wm1[t]); return; }
  t -= 65536;
  if (t < 65536) { ((unsigned short*)(ws + OFF_WM2BF))[t] = f2bf(Wm2[t]); return; }
  t -= 65536;
  if (t < 8192) { ((unsigned short*)(ws + OFF_W2BFG))[t] = f2bf(W2[t]); return; }
}

// ---------------- K0f: feat10 bf16 + jn32 precompute, k-major layout ----------------
__global__ __launch_bounds__(256) void k0f_feat(const float* __restrict__ pos,
                                                const float* __restrict__ dist,
                                                const int* __restrict__ idxp, float* ws) {
  int flag = ((const int*)(ws + OFF_FLAG))[0];
  unsigned short* featg = (unsigned short*)(ws + OFF_AGG1);
  int* jn32 = (int*)(ws + OFF_KVTBF);
  int r = blockIdx.x * 256 + threadIdx.x;        // r = (b*Kn + k)*Nn + n
  int b = r >> 16;
  int n = r & (Nn - 1);
  int k = (r >> 12) & (Kn - 1);
  int fidx = (b * Nn + n) * Kn + k;
  int jn = flag ? idxp[2 * fidx] : idxp[fidx];
  float dd = dist[fidx];
  float pc0 = pos[(b * Nn + n) * 3 + 0], pc1 = pos[(b * Nn + n) * 3 + 1], pc2 = pos[(b * Nn + n) * 3 + 2];
  float pn0 = pos[(b * Nn + jn) * 3 + 0], pn1 = pos[(b * Nn + jn) * 3 + 1], pn2 = pos[(b * Nn + jn) * 3 + 2];
  float f10[10] = {pc0, pc1, pc2, pn0, pn1, pn2, pc0 - pn0, pc1 - pn1, pc2 - pn2, dd};
  union { unsigned short us[16]; uint4 u4[2]; } o;
#pragma unroll
  for (int j = 0; j < 10; ++j) o.us[j] = f2bf(f10[j]);
#pragma unroll
  for (int j = 10; j < 16; ++j) o.us[j] = 0;
  *(uint4*)&featg[r * 16] = o.u4[0];
  *(uint4*)&featg[r * 16 + 8] = o.u4[1];
  jn32[r] = jn;
}

// ---------------- K1: qkv GEMM (MFMA); Q -> normalized bf16, K/V -> bf16 ----------------
__global__ __launch_bounds__(256, 2) void k1_qkv(const float* __restrict__ x, float* ws) {
  __shared__ __align__(16) unsigned short a_lds[32 * 136];  // [n][c] bf16
  __shared__ __align__(16) float qkv_lds[32 * 388];         // [n][m] f32
  const unsigned short* Wq = (const unsigned short*)(ws + OFF_WQKVBF);
  unsigned short* Qnbf = (unsigned short*)(ws + OFF_QNBF);
  unsigned short* KmBF = (unsigned short*)(ws + OFF_KMBF);
  unsigned short* VmBF = (unsigned short*)(ws + OFF_VMBF);
  int b = blockIdx.x >> 7;
  int n0 = (blockIdx.x & 127) << 5;
  int t = threadIdx.x;
  int w = t >> 6, l = t & 63, ml = l & 15, gq = l >> 4;
#pragma unroll
  for (int i = 0; i < 16; ++i) {
    int id = t + 256 * i;
    int c = id >> 5, j = id & 31;
    a_lds[j * 136 + c] = f2bf(x[(b * Cn + c) * Nn + n0 + j]);
  }
  __syncthreads();
  f32x4 acc[2][6];
#pragma unroll
  for (int i = 0; i < 2; ++i)
#pragma unroll
    for (int j = 0; j < 6; ++j) acc[i][j] = (f32x4)0.f;
#pragma unroll
  for (int kc = 0; kc < 4; ++kc) {
    bf16x8 av0 = *(const bf16x8*)&a_lds[ml * 136 + kc * 32 + 8 * gq];
    bf16x8 av1 = *(const bf16x8*)&a_lds[(ml + 16) * 136 + kc * 32 + 8 * gq];
#pragma unroll
    for (int nf = 0; nf < 6; ++nf) {
      int m = 96 * w + 16 * nf + ml;
      bf16x8 bv = *(const bf16x8*)&Wq[m * 128 + kc * 32 + 8 * gq];
      acc[0][nf] = __builtin_amdgcn_mfma_f32_16x16x32_bf16(av0, bv, acc[0][nf], 0, 0, 0);
      acc[1][nf] = __builtin_amdgcn_mfma_f32_16x16x32_bf16(av1, bv, acc[1][nf], 0, 0, 0);
    }
  }
#pragma unroll
  for (int mf = 0; mf < 2; ++mf)
#pragma unroll
    for (int nf = 0; nf < 6; ++nf)
#pragma unroll
      for (int r = 0; r < 4; ++r)
        qkv_lds[(16 * mf + 4 * gq + r) * 388 + 96 * w + 16 * nf + ml] = acc[mf][nf][r];
  __syncthreads();
  // Q normalize -> bf16
  {
    int g = t >> 3, l8 = t & 7;
    float4 q4[4];
    float ss = 0.f;
#pragma unroll
    for (int q = 0; q < 4; ++q) {
      q4[q] = *(const float4*)&qkv_lds[g * 388 + l8 * 16 + 4 * q];
      ss = fmaf(q4[q].x, q4[q].x, ss); ss = fmaf(q4[q].y, q4[q].y, ss);
      ss = fmaf(q4[q].z, q4[q].z, ss); ss = fmaf(q4[q].w, q4[q].w, ss);
    }
    ss += __shfl_xor(ss, 1); ss += __shfl_xor(ss, 2); ss += __shfl_xor(ss, 4);
    float sc = 1.f / fmaxf(sqrtf(ss), 1e-12f);
    union { unsigned short us[8]; uint4 u4; } o0, o1;
#pragma unroll
    for (int q = 0; q < 2; ++q) {
      o0.us[q * 4 + 0] = f2bf(q4[q].x * sc); o0.us[q * 4 + 1] = f2bf(q4[q].y * sc);
      o0.us[q * 4 + 2] = f2bf(q4[q].z * sc); o0.us[q * 4 + 3] = f2bf(q4[q].w * sc);
    }
#pragma unroll
    for (int q = 0; q < 2; ++q) {
      o1.us[q * 4 + 0] = f2bf(q4[2 + q].x * sc); o1.us[q * 4 + 1] = f2bf(q4[2 + q].y * sc);
      o1.us[q * 4 + 2] = f2bf(q4[2 + q].z * sc); o1.us[q * 4 + 3] = f2bf(q4[2 + q].w * sc);
    }
    *(uint4*)&Qnbf[(b * Nn + n0 + g) * Cn + l8 * 16] = o0.u4;
    *(uint4*)&Qnbf[(b * Nn + n0 + g) * Cn + l8 * 16 + 8] = o1.u4;
  }
  // K, V copy-out bf16
#pragma unroll
  for (int i = 0; i < 2; ++i) {
    int id = t + 256 * i;
    int row = id >> 4, c8 = id & 15;
    const float* kp = &qkv_lds[row * 388 + 128 + c8 * 8];
    const float* vp = &qkv_lds[row * 388 + 256 + c8 * 8];
    union { unsigned short us[8]; uint4 u4; } ko, vo;
#pragma unroll
    for (int j = 0; j < 8; ++j) { ko.us[j] = f2bf(kp[j]); vo.us[j] = f2bf(vp[j]); }
    *(uint4*)&KmBF[(b * Nn + n0 + row) * Cn + c8 * 8] = ko.u4;
    *(uint4*)&VmBF[(b * Nn + n0 + row) * Cn + c8 * 8] = vo.u4;
  }
}

// ---------------- K2: kvT[b,k,d,c] += sum_n Vrel[n,d]*Knorm[n,c]  (MFMA, 2-barrier, feat-precomputed) ----------------
#define CH2 8
__global__ __launch_bounds__(256, 2) void k2_kv(const float* __restrict__ W1,
                                                const float* __restrict__ b1,
                                                const float* __restrict__ b2,
                                                float* ws) {
  __shared__ __align__(16) unsigned short h_lds[32 * 72];    // [n][h]
  __shared__ __align__(16) float pe_lds[32 * 132];           // [n][c] f32 (bias folded)
  __shared__ __align__(16) unsigned short KnT[2][128 * 40];  // [c][n-swz] double-buffered
  __shared__ __align__(16) unsigned short VrT[2][128 * 40];  // [d][n-swz] double-buffered

  const unsigned short* KmBF = (const unsigned short*)(ws + OFF_KMBF);
  const unsigned short* VmBF = (const unsigned short*)(ws + OFF_VMBF);
  const unsigned short* W2g = (const unsigned short*)(ws + OFF_W2BFG);
  const unsigned short* featg = (const unsigned short*)(ws + OFF_AGG1);
  const int* jn32 = (const int*)(ws + OFF_KVTBF);
  float* kvt = ws + OFF_KVT32;

  // XCD-locality decode: b in low 2 bits
  int bid = blockIdx.x;
  int b = bid & 3;
  int rest = bid >> 2;
  int k = rest & 15, ch = rest >> 4;
  int t = threadIdx.x;
  int w = t >> 6, l = t & 63;
  int ml = l & 15, gq = l >> 4;

  int g = t >> 3, l8 = t & 7;        // phase A (MLP) mapping
  int nl = (t >> 3) & 7, half = t & 7;
  int n_b2 = 8 * w + nl;             // phase B2 mapping: 8 threads/row, same wave
  int swb = ((w ^ (half & 3)) << 3) + nl;   // swizzled n-position for transposed stores

  float b2v0 = b2[32 * w + ml];
  float b2v1 = b2[32 * w + 16 + ml];

  f32x4 acc[2][8];
#pragma unroll
  for (int i = 0; i < 2; ++i)
#pragma unroll
    for (int j = 0; j < 8; ++j) acc[i][j] = (f32x4)0.f;

  int nbase = ch * 512;
  int base = (b * Kn + k) * Nn;
  union U8 { unsigned short us[8]; uint4 u4; };

  // ---- prologue prefetch for it=0 ----
  U8 fa, fb;
  fa.u4 = *(const uint4*)&featg[(base + nbase + g) * 16];
  fb.u4 = *(const uint4*)&featg[(base + nbase + g) * 16 + 8];
  int jn_b = jn32[base + nbase + n_b2];
  U8 ka, kb, va, vb;
  {
    const unsigned short* krow = &KmBF[(b * Nn + jn_b) * Cn];
    const unsigned short* vrow = &VmBF[(b * Nn + jn_b) * Cn];
    ka.u4 = *(const uint4*)&krow[half * 16];
    kb.u4 = *(const uint4*)&krow[half * 16 + 8];
    va.u4 = *(const uint4*)&vrow[half * 16];
    vb.u4 = *(const uint4*)&vrow[half * 16 + 8];
  }

  for (int it = 0; it < 16; ++it) {
    // ---- Phase A: MLP layer1 from prefetched feat -> h_lds ----
    {
      float f10[10];
#pragma unroll
      for (int j = 0; j < 10; ++j) f10[j] = b2f((j < 8) ? fa.us[j] : fb.us[j - 8]);
      union { unsigned short us[8]; uint4 u4; } hv;
#pragma unroll
      for (int oo = 0; oo < 8; ++oo) {
        int o = l8 * 8 + oo;
        float a = b1[o];
#pragma unroll
        for (int i2 = 0; i2 < 10; ++i2) a = fmaf(W1[o * 10 + i2], f10[i2], a);
        hv.us[oo] = f2bf(fmaxf(a, 0.f));
      }
      *(uint4*)&h_lds[g * 72 + l8 * 8] = hv.u4;
    }
    // issue next-iter feat + jn loads (resolve during C/B1)
    int itn = (it < 15) ? it + 1 : 15;
    int n0n = nbase + itn * 32;
    U8 fan, fbn;
    fan.u4 = *(const uint4*)&featg[(base + n0n + g) * 16];
    fbn.u4 = *(const uint4*)&featg[(base + n0n + g) * 16 + 8];
    int jn_bn = jn32[base + n0n + n_b2];
    __syncthreads();   // S1: h ready; buf[(it-1)&1] ready for C
    // ---- Phase C (prev iter, decoupled buffer) ----
    if (it > 0) {
      const unsigned short* ktp = KnT[(it - 1) & 1];
      const unsigned short* vtp = VrT[(it - 1) & 1];
      bf16x8 av[2];
#pragma unroll
      for (int mf = 0; mf < 2; ++mf) {
        int d = 32 * w + 16 * mf + ml;
        int blk = gq ^ ((2 * w + mf) & 3);
        av[mf] = *(const bf16x8*)&vtp[d * 40 + 8 * blk];
      }
#pragma unroll
      for (int nf = 0; nf < 8; ++nf) {
        int c = 16 * nf + ml;
        int blk = gq ^ (nf & 3);
        bf16x8 bv = *(const bf16x8*)&ktp[c * 40 + 8 * blk];
#pragma unroll
        for (int mf = 0; mf < 2; ++mf)
          acc[mf][nf] = __builtin_amdgcn_mfma_f32_16x16x32_bf16(av[mf], bv, acc[mf][nf], 0, 0, 0);
      }
    }
    // ---- Phase B1 (MFMA): pe[n][c] = h @ W2^T + b2 -> pe_lds f32 ----
    {
      f32x4 pacc[2][2];
#pragma unroll
      for (int i = 0; i < 2; ++i)
#pragma unroll
        for (int j = 0; j < 2; ++j) pacc[i][j] = (f32x4)0.f;
#pragma unroll
      for (int hc = 0; hc < 64; hc += 32) {
        bf16x8 av[2];
#pragma unroll
        for (int mf = 0; mf < 2; ++mf)
          av[mf] = *(const bf16x8*)&h_lds[(ml + 16 * mf) * 72 + hc + 8 * gq];
#pragma unroll
        for (int nf = 0; nf < 2; ++nf) {
          int c = 32 * w + 16 * nf + ml;
          bf16x8 bv = *(const bf16x8*)&W2g[c * 64 + hc + 8 * gq];
          pacc[0][nf] = __builtin_amdgcn_mfma_f32_16x16x32_bf16(av[0], bv, pacc[0][nf], 0, 0, 0);
          pacc[1][nf] = __builtin_amdgcn_mfma_f32_16x16x32_bf16(av[1], bv, pacc[1][nf], 0, 0, 0);
        }
      }
#pragma unroll
      for (int mf = 0; mf < 2; ++mf)
#pragma unroll
        for (int nf = 0; nf < 2; ++nf) {
          int c = 32 * w + 16 * nf + ml;
          float bias = nf ? b2v1 : b2v0;
#pragma unroll
          for (int r = 0; r < 4; ++r)
            pe_lds[(16 * mf + 4 * gq + r) * 132 + c] = pacc[mf][nf][r] + bias;
        }
    }
    __syncthreads();   // S2: pe ready (h consumed)
    // ---- prefetch it+1 K/V rows (hide under B2 compute; consumed at B2(it+1)) ----
    U8 kan, kbn, van, vbn;
    {
      const unsigned short* krow = &KmBF[(b * Nn + jn_bn) * Cn];
      const unsigned short* vrow = &VmBF[(b * Nn + jn_bn) * Cn];
      kan.u4 = *(const uint4*)&krow[half * 16];
      kbn.u4 = *(const uint4*)&krow[half * 16 + 8];
      van.u4 = *(const uint4*)&vrow[half * 16];
      vbn.u4 = *(const uint4*)&vrow[half * 16 + 8];
    }
    // ---- Phase B2: (K/V prefetched) + pe, normalize, direct swizzled transposed stores ----
    {
      float p[16];
#pragma unroll
      for (int q = 0; q < 4; ++q) {
        float4 p4 = *(const float4*)&pe_lds[n_b2 * 132 + half * 16 + 4 * q];
        p[4 * q] = p4.x; p[4 * q + 1] = p4.y; p[4 * q + 2] = p4.z; p[4 * q + 3] = p4.w;
      }
      unsigned short* kdst = KnT[it & 1];
      unsigned short* vdst = VrT[it & 1];
      float kr[16];
      float ss = 0.f;
#pragma unroll
      for (int j = 0; j < 16; ++j) {
        float kg = b2f((j < 8) ? ka.us[j] : kb.us[j - 8]);
        float vg = b2f((j < 8) ? va.us[j] : vb.us[j - 8]);
        kr[j] = kg + p[j];
        float vv = fmaxf(vg + p[j], 0.f);
        ss = fmaf(kr[j], kr[j], ss);
        vdst[(half * 16 + j) * 40 + swb] = f2bf(vv);
      }
      ss += __shfl_xor(ss, 1); ss += __shfl_xor(ss, 2); ss += __shfl_xor(ss, 4);
      float sc = 1.f / fmaxf(sqrtf(ss), 1e-12f);
#pragma unroll
      for (int j = 0; j < 16; ++j)
        kdst[(half * 16 + j) * 40 + swb] = f2bf(kr[j] * sc);
    }
    // rotate prefetched registers
    fa.u4 = fan.u4; fb.u4 = fbn.u4;
    ka.u4 = kan.u4; kb.u4 = kbn.u4; va.u4 = van.u4; vb.u4 = vbn.u4;
  }
  // epilogue: final C on buf[15&1]
  __syncthreads();
  {
    const unsigned short* ktp = KnT[15 & 1];
    const unsigned short* vtp = VrT[15 & 1];
    bf16x8 av[2];
#pragma unroll
    for (int mf = 0; mf < 2; ++mf) {
      int d = 32 * w + 16 * mf + ml;
      int blk = gq ^ ((2 * w + mf) & 3);
      av[mf] = *(const bf16x8*)&vtp[d * 40 + 8 * blk];
    }
#pragma unroll
    for (int nf = 0; nf < 8; ++nf) {
      int c = 16 * nf + ml;
      int blk = gq ^ (nf & 3);
      bf16x8 bv = *(const bf16x8*)&ktp[c * 40 + 8 * blk];
#pragma unroll
      for (int mf = 0; mf < 2; ++mf)
        acc[mf][nf] = __builtin_amdgcn_mfma_f32_16x16x32_bf16(av[mf], bv, acc[mf][nf], 0, 0, 0);
    }
  }
  float* kvp = kvt + (b * Kn + k) * Cn * Cn;
#pragma unroll
  for (int mf = 0; mf < 2; ++mf)
#pragma unroll
    for (int nf = 0; nf < 8; ++nf) {
      int c = 16 * nf + ml;
#pragma unroll
      for (int r = 0; r < 4; ++r) {
        int d = 32 * w + 16 * mf + 4 * gq + r;
        atomicAdd(&kvp[d * Cn + c], acc[mf][nf][r]);
      }
    }
}

// ---------------- K2b: kvT f32 -> bf16 ----------------
__global__ __launch_bounds__(256) void k2b_cvt(float* ws) {
  const float* src = ws + OFF_KVT32;
  unsigned short* dst = (unsigned short*)(ws + OFF_KVTBF);
  int i = blockIdx.x * 256 + threadIdx.x;
  float4 a = *(const float4*)&src[i * 8];
  float4 c = *(const float4*)&src[i * 8 + 4];
  union { unsigned short us[8]; uint4 u4; } o;
  o.us[0] = f2bf(a.x); o.us[1] = f2bf(a.y); o.us[2] = f2bf(a.z); o.us[3] = f2bf(a.w);
  o.us[4] = f2bf(c.x); o.us[5] = f2bf(c.y); o.us[6] = f2bf(c.z); o.us[7] = f2bf(c.w);
  *(uint4*)&dst[i * 8] = o.u4;
}

// ---------------- K3: agg partials via gathered MFMA GEMM ----------------
__global__ __launch_bounds__(256, 4) void k3_agg(const int* __restrict__ idxp, float* ws) {
  __shared__ __align__(16) unsigned short qt[32 * 136];  // [n][c]
  const unsigned short* Qnbf = (const unsigned short*)(ws + OFF_QNBF);
  const unsigned short* kvtbf = (const unsigned short*)(ws + OFF_KVTBF);
  int flag = ((const int*)(ws + OFF_FLAG))[0];

  int bid = blockIdx.x;
  int b = bid & 3;
  int kh = (bid >> 2) & 1;
  int nt = bid >> 3;
  int n0 = nt * 32;
  int t = threadIdx.x;
  int w = t >> 6, l = t & 63;
  int ml = l & 15, gq = l >> 4;

  f32x4 acc[2][2];
#pragma unroll
  for (int i = 0; i < 2; ++i)
#pragma unroll
    for (int j = 0; j < 2; ++j) acc[i][j] = (f32x4)0.f;

  for (int kk = 0; kk < 8; ++kk) {
    int k = kh * 8 + kk;
    __syncthreads();
#pragma unroll
    for (int i = 0; i < 2; ++i) {
      int id = t + 256 * i;
      int row = id >> 4, c16 = id & 15;
      int fidx = (b * Nn + n0 + row) * Kn + k;
      int jn = flag ? idxp[2 * fidx] : idxp[fidx];
      uint4 v = *(const uint4*)&Qnbf[(b * Nn + jn) * Cn + c16 * 8];
      *(uint4*)&qt[row * 136 + c16 * 8] = v;
    }
    __syncthreads();
    const unsigned short* kvp = &kvtbf[(b * Kn + k) * Cn * Cn];
#pragma unroll
    for (int c0 = 0; c0 < 128; c0 += 32) {
      bf16x8 a0 = *(const bf16x8*)&qt[ml * 136 + c0 + 8 * gq];
      bf16x8 a1 = *(const bf16x8*)&qt[(ml + 16) * 136 + c0 + 8 * gq];
#pragma unroll
      for (int nf = 0; nf < 2; ++nf) {
        int d = 32 * w + 16 * nf + ml;
        bf16x8 bv = *(const bf16x8*)&kvp[d * Cn + c0 + 8 * gq];
        acc[0][nf] = __builtin_amdgcn_mfma_f32_16x16x32_bf16(a0, bv, acc[0][nf], 0, 0, 0);
        acc[1][nf] = __builtin_amdgcn_mfma_f32_16x16x32_bf16(a1, bv, acc[1][nf], 0, 0, 0);
      }
    }
  }
  float* ag = ws + (kh ? OFF_AGG1 : OFF_AGG0);
#pragma unroll
  for (int mf = 0; mf < 2; ++mf)
#pragma unroll
    for (int nf = 0; nf < 2; ++nf) {
      int d = 32 * w + 16 * nf + ml;
#pragma unroll
      for (int r = 0; r < 4; ++r) {
        int n = n0 + 16 * mf + 4 * gq + r;
        ag[(b * Nn + n) * Cn + d] = acc[mf][nf][r];
      }
    }
}

// ---------------- K4: out = relu(agg@Wm1^T+bm1)@Wm2^T + bm2 + xt  (MFMA) ----------------
__global__ __launch_bounds__(256, 2) void k4_mlp(const float* __restrict__ x,
                                                 const float* __restrict__ bm1,
                                                 const float* __restrict__ bm2,
                                                 float* __restrict__ out, float* ws) {
  __shared__ __align__(16) unsigned short a_lds[32 * 136];  // [n][c] bf16
  __shared__ __align__(16) unsigned short h_lds[32 * 520];  // [n][h] bf16
  __shared__ float out_s[128 * 33];                          // [co][n]
  const float* agg0 = ws + OFF_AGG0;
  const float* agg1 = ws + OFF_AGG1;
  const unsigned short* Wm1bf = (const unsigned short*)(ws + OFF_WM1BF);
  const unsigned short* Wm2bf = (const unsigned short*)(ws + OFF_WM2BF);
  const float invN = 1.f / (float)Nn;
  int b = blockIdx.x >> 7;
  int n0 = (blockIdx.x & 127) << 5;
  int t = threadIdx.x;
  int w = t >> 6, l = t & 63, ml = l & 15, gq = l >> 4;
#pragma unroll
  for (int i = 0; i < 4; ++i) {
    int id = t + 256 * i;
    int row = id >> 5, c4 = id & 31;
    int off = (b * Nn + n0 + row) * Cn + c4 * 4;
    float4 v0 = *(const float4*)&agg0[off];
    float4 v1 = *(const float4*)&agg1[off];
    union { unsigned short us[4]; uint2 u2; } o;
    o.us[0] = f2bf((v0.x + v1.x) * invN); o.us[1] = f2bf((v0.y + v1.y) * invN);
    o.us[2] = f2bf((v0.z + v1.z) * invN); o.us[3] = f2bf((v0.w + v1.w) * invN);
    *(uint2*)&a_lds[row * 136 + c4 * 4] = o.u2;
  }
  __syncthreads();
  // layer1: wave w -> h cols [128w, 128w+128)
  {
    f32x4 hacc[2][8];
#pragma unroll
    for (int i = 0; i < 2; ++i)
#pragma unroll
      for (int j = 0; j < 8; ++j) hacc[i][j] = (f32x4)0.f;
#pragma unroll
    for (int kc = 0; kc < 4; ++kc) {
      bf16x8 av0 = *(const bf16x8*)&a_lds[ml * 136 + kc * 32 + 8 * gq];
      bf16x8 av1 = *(const bf16x8*)&a_lds[(ml + 16) * 136 + kc * 32 + 8 * gq];
#pragma unroll
      for (int nf = 0; nf < 8; ++nf) {
        int h = 128 * w + 16 * nf + ml;
        bf16x8 bv = *(const bf16x8*)&Wm1bf[h * 128 + kc * 32 + 8 * gq];
        hacc[0][nf] = __builtin_amdgcn_mfma_f32_16x16x32_bf16(av0, bv, hacc[0][nf], 0, 0, 0);
        hacc[1][nf] = __builtin_amdgcn_mfma_f32_16x16x32_bf16(av1, bv, hacc[1][nf], 0, 0, 0);
      }
    }
#pragma unroll
    for (int mf = 0; mf < 2; ++mf)
#pragma unroll
      for (int nf = 0; nf < 8; ++nf) {
        int h = 128 * w + 16 * nf + ml;
        float bias = bm1[h];
#pragma unroll
        for (int r = 0; r < 4; ++r)
          h_lds[(16 * mf + 4 * gq + r) * 520 + h] = f2bf(fmaxf(hacc[mf][nf][r] + bias, 0.f));
      }
  }
  __syncthreads();
  // layer2: wave w -> co cols [32w, 32w+32)
  {
    f32x4 oacc[2][2];
#pragma unroll
    for (int i = 0; i < 2; ++i)
#pragma unroll
      for (int j = 0; j < 2; ++j) oacc[i][j] = (f32x4)0.f;
#pragma unroll
    for (int kc = 0; kc < 16; ++kc) {
      bf16x8 av0 = *(const bf16x8*)&h_lds[ml * 520 + kc * 32 + 8 * gq];
      bf16x8 av1 = *(const bf16x8*)&h_lds[(ml + 16) * 520 + kc * 32 + 8 * gq];
#pragma unroll
      for (int nf = 0; nf < 2; ++nf) {
        int co = 32 * w + 16 * nf + ml;
        bf16x8 bv = *(const bf16x8*)&Wm2bf[co * 512 + kc * 32 + 8 * gq];
        oacc[0][nf] = __builtin_amdgcn_mfma_f32_16x16x32_bf16(av0, bv, oacc[0][nf], 0, 0, 0);
        oacc[1][nf] = __builtin_amdgcn_mfma_f32_16x16x32_bf16(av1, bv, oacc[1][nf], 0, 0, 0);
      }
    }
#pragma unroll
    for (int mf = 0; mf < 2; ++mf)
#pragma unroll
      for (int nf = 0; nf < 2; ++nf) {
        int co = 32 * w + 16 * nf + ml;
        float bias = bm2[co];
#pragma unroll
        for (int r = 0; r < 4; ++r)
          out_s[co * 33 + 16 * mf + 4 * gq + r] = oacc[mf][nf][r] + bias;
      }
  }
  __syncthreads();
#pragma unroll
  for (int i = 0; i < 16; ++i) {
    int id = t + 256 * i;
    int co = id >> 5, j = id & 31;
    out[(b * Cn + co) * Nn + n0 + j] = out_s[co * 33 + j] + x[(b * Cn + co) * Nn + n0 + j];
  }
}

extern "C" void kernel_launch(void* const* d_in, const int* in_sizes, int n_in,
                              void* d_out, int out_size, void* d_ws, size_t ws_size,
                              hipStream_t stream) {
  const float* pos  = (const float*)d_in[0];
  const float* x    = (const float*)d_in[1];
  const int*   idx  = (const int*)d_in[2];
  const float* dist = (const float*)d_in[3];
  const float* Wqkv = (const float*)d_in[4];
  const float* W1   = (const float*)d_in[5];
  const float* b1   = (const float*)d_in[6];
  const float* W2   = (const float*)d_in[7];
  const float* b2   = (const float*)d_in[8];
  const float* Wm1  = (const float*)d_in[9];
  const float* bm1  = (const float*)d_in[10];
  const float* Wm2  = (const float*)d_in[11];
  const float* bm2  = (const float*)d_in[12];
  float* out = (float*)d_out;
  float* ws = (float*)d_ws;

  hipMemsetAsync(ws + OFF_KVT32, 0, (size_t)Bn * Kn * Cn * Cn * sizeof(float), stream);
  hipLaunchKernelGGL(k0_prep, dim3(736), dim3(256), 0, stream, Wqkv, Wm1, Wm2, W2, idx, ws);
  hipLaunchKernelGGL(k0f_feat, dim3(1024), dim3(256), 0, stream, pos, dist, idx, ws);
  hipLaunchKernelGGL(k1_qkv, dim3(Bn * 128), dim3(256), 0, stream, x, ws);
  hipLaunchKernelGGL(k2_kv, dim3(Bn * Kn * CH2), dim3(256), 0, stream, W1, b1, b2, ws);
  hipLaunchKernelGGL(k2b_cvt, dim3(512), dim3(256), 0, stream, ws);
  hipLaunchKernelGGL(k3_agg, dim3(Bn * 2 * 128), dim3(256), 0, stream, idx, ws);
  hipLaunchKernelGGL(k4_mlp, dim3(Bn * 128), dim3(256), 0, stream, x, bm1, bm2, out, ws);
}

// Round 16
// 147.344 us; speedup vs baseline: 1.0731x; 1.0731x over previous
//
#include <hip/hip_runtime.h>
#include <math.h>

#define Bn 4
#define Nn 4096
#define Kn 16
#define Cn 128
#define HIDn 64

// ws layout (float offsets)
#define OFF_WQKVBF 0          // 49152 bf16 = 24576 f
#define OFF_WM1BF  24576      // 65536 bf16 = 32768 f
#define OFF_WM2BF  57344      // 65536 bf16 = 32768 f
#define OFF_W2BFG  90112      // 8192 bf16 = 4096 f
#define OFF_QNBF   95232      // 1048576 f
#define OFF_KMBF   1143808    // 1048576 f
#define OFF_VMBF   2192384    // 1048576 f
#define OFF_KVT32  3240960    // B*K*C*C f32 (atomic target, [b,k,d,c])
#define OFF_KVTBF  4289536    // 524288 f
#define OFF_AGG0   4813824    // 2097152 f
#define OFF_AGG1   6910976    // 2097152 f
#define OFF_FLAG   9008128    // 1 int

typedef short bf16x8 __attribute__((ext_vector_type(8)));
typedef float f32x4 __attribute__((ext_vector_type(4)));

__device__ inline unsigned short f2bf(float f) {
  union { float f; unsigned u; } v; v.f = f;
  unsigned r = v.u + 0x7fffu + ((v.u >> 16) & 1u);
  return (unsigned short)(r >> 16);
}
__device__ inline float b2f(unsigned short s) {
  union { unsigned u; float f; } v; v.u = ((unsigned)s) << 16; return v.f;
}

// ---------------- K0: weight bf16 casts + idx dtype probe ----------------
__global__ void k0_prep(const float* __restrict__ Wqkv,
                        const float* __restrict__ Wm1, const float* __restrict__ Wm2,
                        const float* __restrict__ W2,
                        const int* __restrict__ idx_raw, float* ws) {
  if (blockIdx.x == 0 && threadIdx.x == 0) {
    int any = 0;
    for (int i = 0; i < 64; ++i) any |= idx_raw[2 * i + 1];
    ((int*)(ws + OFF_FLAG))[0] = (any == 0) ? 1 : 0;   // 1 => idx is int64
  }
  int t = blockIdx.x * 256 + threadIdx.x;
  if (t < 49152) { ((unsigned short*)(ws + OFF_WQKVBF))[t] = f2bf(Wqkv[t]); return; }
  t -= 49152;
  if (t < 65536) { ((unsigned short*)(ws + OFF_WM1BF))[t] = f2bf(Wm1[t]); return; }
  t -= 65536;
  if (t < 65536) { ((unsigned short*)(ws + OFF_WM2BF))[t] = f2bf(Wm2[t]); return; }
  t -= 65536;
  if (t < 8192) { ((unsigned short*)(ws + OFF_W2BFG))[t] = f2bf(W2[t]); return; }
}

// ---------------- K1: qkv GEMM (MFMA); Q -> normalized bf16, K/V -> bf16 ----------------
__global__ __launch_bounds__(256, 2) void k1_qkv(const float* __restrict__ x, float* ws) {
  __shared__ __align__(16) unsigned short a_lds[32 * 136];  // [n][c] bf16
  __shared__ __align__(16) float qkv_lds[32 * 388];         // [n][m] f32
  const unsigned short* Wq = (const unsigned short*)(ws + OFF_WQKVBF);
  unsigned short* Qnbf = (unsigned short*)(ws + OFF_QNBF);
  unsigned short* KmBF = (unsigned short*)(ws + OFF_KMBF);
  unsigned short* VmBF = (unsigned short*)(ws + OFF_VMBF);
  int b = blockIdx.x >> 7;
  int n0 = (blockIdx.x & 127) << 5;
  int t = threadIdx.x;
  int w = t >> 6, l = t & 63, ml = l & 15, gq = l >> 4;
#pragma unroll
  for (int i = 0; i < 16; ++i) {
    int id = t + 256 * i;
    int c = id >> 5, j = id & 31;
    a_lds[j * 136 + c] = f2bf(x[(b * Cn + c) * Nn + n0 + j]);
  }
  __syncthreads();
  f32x4 acc[2][6];
#pragma unroll
  for (int i = 0; i < 2; ++i)
#pragma unroll
    for (int j = 0; j < 6; ++j) acc[i][j] = (f32x4)0.f;
#pragma unroll
  for (int kc = 0; kc < 4; ++kc) {
    bf16x8 av0 = *(const bf16x8*)&a_lds[ml * 136 + kc * 32 + 8 * gq];
    bf16x8 av1 = *(const bf16x8*)&a_lds[(ml + 16) * 136 + kc * 32 + 8 * gq];
#pragma unroll
    for (int nf = 0; nf < 6; ++nf) {
      int m = 96 * w + 16 * nf + ml;
      bf16x8 bv = *(const bf16x8*)&Wq[m * 128 + kc * 32 + 8 * gq];
      acc[0][nf] = __builtin_amdgcn_mfma_f32_16x16x32_bf16(av0, bv, acc[0][nf], 0, 0, 0);
      acc[1][nf] = __builtin_amdgcn_mfma_f32_16x16x32_bf16(av1, bv, acc[1][nf], 0, 0, 0);
    }
  }
#pragma unroll
  for (int mf = 0; mf < 2; ++mf)
#pragma unroll
    for (int nf = 0; nf < 6; ++nf)
#pragma unroll
      for (int r = 0; r < 4; ++r)
        qkv_lds[(16 * mf + 4 * gq + r) * 388 + 96 * w + 16 * nf + ml] = acc[mf][nf][r];
  __syncthreads();
  // Q normalize -> bf16
  {
    int g = t >> 3, l8 = t & 7;
    float4 q4[4];
    float ss = 0.f;
#pragma unroll
    for (int q = 0; q < 4; ++q) {
      q4[q] = *(const float4*)&qkv_lds[g * 388 + l8 * 16 + 4 * q];
      ss = fmaf(q4[q].x, q4[q].x, ss); ss = fmaf(q4[q].y, q4[q].y, ss);
      ss = fmaf(q4[q].z, q4[q].z, ss); ss = fmaf(q4[q].w, q4[q].w, ss);
    }
    ss += __shfl_xor(ss, 1); ss += __shfl_xor(ss, 2); ss += __shfl_xor(ss, 4);
    float sc = 1.f / fmaxf(sqrtf(ss), 1e-12f);
    union { unsigned short us[8]; uint4 u4; } o0, o1;
#pragma unroll
    for (int q = 0; q < 2; ++q) {
      o0.us[q * 4 + 0] = f2bf(q4[q].x * sc); o0.us[q * 4 + 1] = f2bf(q4[q].y * sc);
      o0.us[q * 4 + 2] = f2bf(q4[q].z * sc); o0.us[q * 4 + 3] = f2bf(q4[q].w * sc);
    }
#pragma unroll
    for (int q = 0; q < 2; ++q) {
      o1.us[q * 4 + 0] = f2bf(q4[2 + q].x * sc); o1.us[q * 4 + 1] = f2bf(q4[2 + q].y * sc);
      o1.us[q * 4 + 2] = f2bf(q4[2 + q].z * sc); o1.us[q * 4 + 3] = f2bf(q4[2 + q].w * sc);
    }
    *(uint4*)&Qnbf[(b * Nn + n0 + g) * Cn + l8 * 16] = o0.u4;
    *(uint4*)&Qnbf[(b * Nn + n0 + g) * Cn + l8 * 16 + 8] = o1.u4;
  }
  // K, V copy-out bf16
#pragma unroll
  for (int i = 0; i < 2; ++i) {
    int id = t + 256 * i;
    int row = id >> 4, c8 = id & 15;
    const float* kp = &qkv_lds[row * 388 + 128 + c8 * 8];
    const float* vp = &qkv_lds[row * 388 + 256 + c8 * 8];
    union { unsigned short us[8]; uint4 u4; } ko, vo;
#pragma unroll
    for (int j = 0; j < 8; ++j) { ko.us[j] = f2bf(kp[j]); vo.us[j] = f2bf(vp[j]); }
    *(uint4*)&KmBF[(b * Nn + n0 + row) * Cn + c8 * 8] = ko.u4;
    *(uint4*)&VmBF[(b * Nn + n0 + row) * Cn + c8 * 8] = vo.u4;
  }
}

// ---------------- K2: kvT[b,k,d,c] += sum_n Vrel[n,d]*Knorm[n,c]  (MFMA, 2-barrier, no T-phase) ----------------
#define CH2 8
__global__ __launch_bounds__(256, 2) void k2_kv(const float* __restrict__ pos,
                                                const float* __restrict__ dist,
                                                const int* __restrict__ idxp,
                                                const float* __restrict__ W1,
                                                const float* __restrict__ b1,
                                                const float* __restrict__ b2,
                                                float* ws) {
  __shared__ __align__(16) unsigned short h_lds[32 * 72];    // [n][h]
  __shared__ __align__(16) float pe_lds[32 * 132];           // [n][c] f32 (bias folded)
  __shared__ __align__(16) unsigned short KnT[2][128 * 40];  // [c][n-swz] double-buffered
  __shared__ __align__(16) unsigned short VrT[2][128 * 40];  // [d][n-swz] double-buffered

  const unsigned short* KmBF = (const unsigned short*)(ws + OFF_KMBF);
  const unsigned short* VmBF = (const unsigned short*)(ws + OFF_VMBF);
  const unsigned short* W2g = (const unsigned short*)(ws + OFF_W2BFG);
  float* kvt = ws + OFF_KVT32;
  int flag = ((const int*)(ws + OFF_FLAG))[0];

  // XCD-locality decode: b in low 2 bits
  int bid = blockIdx.x;
  int b = bid & 3;
  int rest = bid >> 2;
  int k = rest & 15, ch = rest >> 4;
  int t = threadIdx.x;
  int w = t >> 6, l = t & 63;
  int ml = l & 15, gq = l >> 4;

  int g = t >> 3, l8 = t & 7;        // phase A (MLP) mapping
  int nl = (t >> 3) & 7, half = t & 7;
  int n_b2 = 8 * w + nl;             // phase B2 mapping: 8 threads/row, same wave
  int swb = ((w ^ (half & 3)) << 3) + nl;   // swizzled n-position for transposed stores

  float b2v0 = b2[32 * w + ml];
  float b2v1 = b2[32 * w + 16 + ml];

  f32x4 acc[2][8];
#pragma unroll
  for (int i = 0; i < 2; ++i)
#pragma unroll
    for (int j = 0; j < 8; ++j) acc[i][j] = (f32x4)0.f;

  int nbase = ch * 512;
  union U8 { unsigned short us[8]; uint4 u4; };

  // ---- prologue prefetch for it=0 ----
  int fidx_m = (b * Nn + nbase + g) * Kn + k;
  int jn_m = flag ? idxp[2 * fidx_m] : idxp[fidx_m];
  float dd = dist[fidx_m];
  float pc0 = pos[(b * Nn + nbase + g) * 3 + 0];
  float pc1 = pos[(b * Nn + nbase + g) * 3 + 1];
  float pc2 = pos[(b * Nn + nbase + g) * 3 + 2];
  float pn0 = pos[(b * Nn + jn_m) * 3 + 0];
  float pn1 = pos[(b * Nn + jn_m) * 3 + 1];
  float pn2 = pos[(b * Nn + jn_m) * 3 + 2];
  int fidx_b = (b * Nn + nbase + n_b2) * Kn + k;
  int jn_b = flag ? idxp[2 * fidx_b] : idxp[fidx_b];
  U8 ka, kb, va, vb;
  {
    const unsigned short* krow = &KmBF[(b * Nn + jn_b) * Cn];
    const unsigned short* vrow = &VmBF[(b * Nn + jn_b) * Cn];
    ka.u4 = *(const uint4*)&krow[half * 16];
    kb.u4 = *(const uint4*)&krow[half * 16 + 8];
    va.u4 = *(const uint4*)&vrow[half * 16];
    vb.u4 = *(const uint4*)&vrow[half * 16 + 8];
  }

  for (int it = 0; it < 16; ++it) {
    // ---- Phase A: MLP layer1 from prefetched regs -> h_lds ----
    {
      float f10[10] = {pc0, pc1, pc2, pn0, pn1, pn2, pc0 - pn0, pc1 - pn1, pc2 - pn2, dd};
      union { unsigned short us[8]; uint4 u4; } hv;
#pragma unroll
      for (int oo = 0; oo < 8; ++oo) {
        int o = l8 * 8 + oo;
        float a = b1[o];
#pragma unroll
        for (int i2 = 0; i2 < 10; ++i2) a = fmaf(W1[o * 10 + i2], f10[i2], a);
        hv.us[oo] = f2bf(fmaxf(a, 0.f));
      }
      *(uint4*)&h_lds[g * 72 + l8 * 8] = hv.u4;
    }
    // issue next-iter idx + dist loads (resolve during C/B1)
    int itn = (it < 15) ? it + 1 : 15;
    int n0n = nbase + itn * 32;
    int fidx_mn = (b * Nn + n0n + g) * Kn + k;
    int jn_mn = flag ? idxp[2 * fidx_mn] : idxp[fidx_mn];
    float ddn = dist[fidx_mn];
    int fidx_bn = (b * Nn + n0n + n_b2) * Kn + k;
    int jn_bn = flag ? idxp[2 * fidx_bn] : idxp[fidx_bn];
    __syncthreads();   // S1: h ready; buf[(it-1)&1] ready for C
    // ---- Phase C (prev iter, decoupled buffer) ----
    if (it > 0) {
      const unsigned short* ktp = KnT[(it - 1) & 1];
      const unsigned short* vtp = VrT[(it - 1) & 1];
      bf16x8 av[2];
#pragma unroll
      for (int mf = 0; mf < 2; ++mf) {
        int d = 32 * w + 16 * mf + ml;
        int blk = gq ^ ((2 * w + mf) & 3);
        av[mf] = *(const bf16x8*)&vtp[d * 40 + 8 * blk];
      }
#pragma unroll
      for (int nf = 0; nf < 8; ++nf) {
        int c = 16 * nf + ml;
        int blk = gq ^ (nf & 3);
        bf16x8 bv = *(const bf16x8*)&ktp[c * 40 + 8 * blk];
#pragma unroll
        for (int mf = 0; mf < 2; ++mf)
          acc[mf][nf] = __builtin_amdgcn_mfma_f32_16x16x32_bf16(av[mf], bv, acc[mf][nf], 0, 0, 0);
      }
    }
    // ---- Phase B1 (MFMA): pe[n][c] = h @ W2^T + b2 -> pe_lds f32 ----
    {
      f32x4 pacc[2][2];
#pragma unroll
      for (int i = 0; i < 2; ++i)
#pragma unroll
        for (int j = 0; j < 2; ++j) pacc[i][j] = (f32x4)0.f;
#pragma unroll
      for (int hc = 0; hc < 64; hc += 32) {
        bf16x8 av[2];
#pragma unroll
        for (int mf = 0; mf < 2; ++mf)
          av[mf] = *(const bf16x8*)&h_lds[(ml + 16 * mf) * 72 + hc + 8 * gq];
#pragma unroll
        for (int nf = 0; nf < 2; ++nf) {
          int c = 32 * w + 16 * nf + ml;
          bf16x8 bv = *(const bf16x8*)&W2g[c * 64 + hc + 8 * gq];
          pacc[0][nf] = __builtin_amdgcn_mfma_f32_16x16x32_bf16(av[0], bv, pacc[0][nf], 0, 0, 0);
          pacc[1][nf] = __builtin_amdgcn_mfma_f32_16x16x32_bf16(av[1], bv, pacc[1][nf], 0, 0, 0);
        }
      }
#pragma unroll
      for (int mf = 0; mf < 2; ++mf)
#pragma unroll
        for (int nf = 0; nf < 2; ++nf) {
          int c = 32 * w + 16 * nf + ml;
          float bias = nf ? b2v1 : b2v0;
#pragma unroll
          for (int r = 0; r < 4; ++r)
            pe_lds[(16 * mf + 4 * gq + r) * 132 + c] = pacc[mf][nf][r] + bias;
        }
    }
    __syncthreads();   // S2: pe ready (h consumed)
    // ---- prefetch it+1 pos + K/V rows EARLY (hide under B2 compute) ----
    float pc0n = pos[(b * Nn + n0n + g) * 3 + 0];
    float pc1n = pos[(b * Nn + n0n + g) * 3 + 1];
    float pc2n = pos[(b * Nn + n0n + g) * 3 + 2];
    float pn0n = pos[(b * Nn + jn_mn) * 3 + 0];
    float pn1n = pos[(b * Nn + jn_mn) * 3 + 1];
    float pn2n = pos[(b * Nn + jn_mn) * 3 + 2];
    U8 kan, kbn, van, vbn;
    {
      const unsigned short* krow = &KmBF[(b * Nn + jn_bn) * Cn];
      const unsigned short* vrow = &VmBF[(b * Nn + jn_bn) * Cn];
      kan.u4 = *(const uint4*)&krow[half * 16];
      kbn.u4 = *(const uint4*)&krow[half * 16 + 8];
      van.u4 = *(const uint4*)&vrow[half * 16];
      vbn.u4 = *(const uint4*)&vrow[half * 16 + 8];
    }
    // ---- Phase B2: (K/V prefetched) + pe, normalize, direct swizzled transposed stores ----
    {
      float p[16];
#pragma unroll
      for (int q = 0; q < 4; ++q) {
        float4 p4 = *(const float4*)&pe_lds[n_b2 * 132 + half * 16 + 4 * q];
        p[4 * q] = p4.x; p[4 * q + 1] = p4.y; p[4 * q + 2] = p4.z; p[4 * q + 3] = p4.w;
      }
      unsigned short* kdst = KnT[it & 1];
      unsigned short* vdst = VrT[it & 1];
      float kr[16];
      float ss = 0.f;
#pragma unroll
      for (int j = 0; j < 16; ++j) {
        float kg = b2f((j < 8) ? ka.us[j] : kb.us[j - 8]);
        float vg = b2f((j < 8) ? va.us[j] : vb.us[j - 8]);
        kr[j] = kg + p[j];
        float vv = fmaxf(vg + p[j], 0.f);
        ss = fmaf(kr[j], kr[j], ss);
        vdst[(half * 16 + j) * 40 + swb] = f2bf(vv);
      }
      ss += __shfl_xor(ss, 1); ss += __shfl_xor(ss, 2); ss += __shfl_xor(ss, 4);
      float sc = 1.f / fmaxf(sqrtf(ss), 1e-12f);
#pragma unroll
      for (int j = 0; j < 16; ++j)
        kdst[(half * 16 + j) * 40 + swb] = f2bf(kr[j] * sc);
    }
    // rotate prefetched registers
    dd = ddn;
    pc0 = pc0n; pc1 = pc1n; pc2 = pc2n;
    pn0 = pn0n; pn1 = pn1n; pn2 = pn2n;
    ka.u4 = kan.u4; kb.u4 = kbn.u4; va.u4 = van.u4; vb.u4 = vbn.u4;
  }
  // epilogue: final C on buf[15&1]
  __syncthreads();
  {
    const unsigned short* ktp = KnT[15 & 1];
    const unsigned short* vtp = VrT[15 & 1];
    bf16x8 av[2];
#pragma unroll
    for (int mf = 0; mf < 2; ++mf) {
      int d = 32 * w + 16 * mf + ml;
      int blk = gq ^ ((2 * w + mf) & 3);
      av[mf] = *(const bf16x8*)&vtp[d * 40 + 8 * blk];
    }
#pragma unroll
    for (int nf = 0; nf < 8; ++nf) {
      int c = 16 * nf + ml;
      int blk = gq ^ (nf & 3);
      bf16x8 bv = *(const bf16x8*)&ktp[c * 40 + 8 * blk];
#pragma unroll
      for (int mf = 0; mf < 2; ++mf)
        acc[mf][nf] = __builtin_amdgcn_mfma_f32_16x16x32_bf16(av[mf], bv, acc[mf][nf], 0, 0, 0);
    }
  }
  float* kvp = kvt + (b * Kn + k) * Cn * Cn;
#pragma unroll
  for (int mf = 0; mf < 2; ++mf)
#pragma unroll
    for (int nf = 0; nf < 8; ++nf) {
      int c = 16 * nf + ml;
#pragma unroll
      for (int r = 0; r < 4; ++r) {
        int d = 32 * w + 16 * mf + 4 * gq + r;
        atomicAdd(&kvp[d * Cn + c], acc[mf][nf][r]);
      }
    }
}

// ---------------- K2b: kvT f32 -> bf16 ----------------
__global__ __launch_bounds__(256) void k2b_cvt(float* ws) {
  const float* src = ws + OFF_KVT32;
  unsigned short* dst = (unsigned short*)(ws + OFF_KVTBF);
  int i = blockIdx.x * 256 + threadIdx.x;
  float4 a = *(const float4*)&src[i * 8];
  float4 c = *(const float4*)&src[i * 8 + 4];
  union { unsigned short us[8]; uint4 u4; } o;
  o.us[0] = f2bf(a.x); o.us[1] = f2bf(a.y); o.us[2] = f2bf(a.z); o.us[3] = f2bf(a.w);
  o.us[4] = f2bf(c.x); o.us[5] = f2bf(c.y); o.us[6] = f2bf(c.z); o.us[7] = f2bf(c.w);
  *(uint4*)&dst[i * 8] = o.u4;
}

// ---------------- K3: agg partials via gathered MFMA GEMM ----------------
__global__ __launch_bounds__(256, 4) void k3_agg(const int* __restrict__ idxp, float* ws) {
  __shared__ __align__(16) unsigned short qt[32 * 136];  // [n][c]
  const unsigned short* Qnbf = (const unsigned short*)(ws + OFF_QNBF);
  const unsigned short* kvtbf = (const unsigned short*)(ws + OFF_KVTBF);
  int flag = ((const int*)(ws + OFF_FLAG))[0];

  int bid = blockIdx.x;
  int b = bid & 3;
  int kh = (bid >> 2) & 1;
  int nt = bid >> 3;
  int n0 = nt * 32;
  int t = threadIdx.x;
  int w = t >> 6, l = t & 63;
  int ml = l & 15, gq = l >> 4;

  f32x4 acc[2][2];
#pragma unroll
  for (int i = 0; i < 2; ++i)
#pragma unroll
    for (int j = 0; j < 2; ++j) acc[i][j] = (f32x4)0.f;

  for (int kk = 0; kk < 8; ++kk) {
    int k = kh * 8 + kk;
    __syncthreads();
#pragma unroll
    for (int i = 0; i < 2; ++i) {
      int id = t + 256 * i;
      int row = id >> 4, c16 = id & 15;
      int fidx = (b * Nn + n0 + row) * Kn + k;
      int jn = flag ? idxp[2 * fidx] : idxp[fidx];
      uint4 v = *(const uint4*)&Qnbf[(b * Nn + jn) * Cn + c16 * 8];
      *(uint4*)&qt[row * 136 + c16 * 8] = v;
    }
    __syncthreads();
    const unsigned short* kvp = &kvtbf[(b * Kn + k) * Cn * Cn];
#pragma unroll
    for (int c0 = 0; c0 < 128; c0 += 32) {
      bf16x8 a0 = *(const bf16x8*)&qt[ml * 136 + c0 + 8 * gq];
      bf16x8 a1 = *(const bf16x8*)&qt[(ml + 16) * 136 + c0 + 8 * gq];
#pragma unroll
      for (int nf = 0; nf < 2; ++nf) {
        int d = 32 * w + 16 * nf + ml;
        bf16x8 bv = *(const bf16x8*)&kvp[d * Cn + c0 + 8 * gq];
        acc[0][nf] = __builtin_amdgcn_mfma_f32_16x16x32_bf16(a0, bv, acc[0][nf], 0, 0, 0);
        acc[1][nf] = __builtin_amdgcn_mfma_f32_16x16x32_bf16(a1, bv, acc[1][nf], 0, 0, 0);
      }
    }
  }
  float* ag = ws + (kh ? OFF_AGG1 : OFF_AGG0);
#pragma unroll
  for (int mf = 0; mf < 2; ++mf)
#pragma unroll
    for (int nf = 0; nf < 2; ++nf) {
      int d = 32 * w + 16 * nf + ml;
#pragma unroll
      for (int r = 0; r < 4; ++r) {
        int n = n0 + 16 * mf + 4 * gq + r;
        ag[(b * Nn + n) * Cn + d] = acc[mf][nf][r];
      }
    }
}

// ---------------- K4: out = relu(agg@Wm1^T+bm1)@Wm2^T + bm2 + xt  (MFMA) ----------------
__global__ __launch_bounds__(256, 2) void k4_mlp(const float* __restrict__ x,
                                                 const float* __restrict__ bm1,
                                                 const float* __restrict__ bm2,
                                                 float* __restrict__ out, float* ws) {
  __shared__ __align__(16) unsigned short a_lds[32 * 136];  // [n][c] bf16
  __shared__ __align__(16) unsigned short h_lds[32 * 520];  // [n][h] bf16
  __shared__ float out_s[128 * 33];                          // [co][n]
  const float* agg0 = ws + OFF_AGG0;
  const float* agg1 = ws + OFF_AGG1;
  const unsigned short* Wm1bf = (const unsigned short*)(ws + OFF_WM1BF);
  const unsigned short* Wm2bf = (const unsigned short*)(ws + OFF_WM2BF);
  const float invN = 1.f / (float)Nn;
  int b = blockIdx.x >> 7;
  int n0 = (blockIdx.x & 127) << 5;
  int t = threadIdx.x;
  int w = t >> 6, l = t & 63, ml = l & 15, gq = l >> 4;
#pragma unroll
  for (int i = 0; i < 4; ++i) {
    int id = t + 256 * i;
    int row = id >> 5, c4 = id & 31;
    int off = (b * Nn + n0 + row) * Cn + c4 * 4;
    float4 v0 = *(const float4*)&agg0[off];
    float4 v1 = *(const float4*)&agg1[off];
    union { unsigned short us[4]; uint2 u2; } o;
    o.us[0] = f2bf((v0.x + v1.x) * invN); o.us[1] = f2bf((v0.y + v1.y) * invN);
    o.us[2] = f2bf((v0.z + v1.z) * invN); o.us[3] = f2bf((v0.w + v1.w) * invN);
    *(uint2*)&a_lds[row * 136 + c4 * 4] = o.u2;
  }
  __syncthreads();
  // layer1: wave w -> h cols [128w, 128w+128)
  {
    f32x4 hacc[2][8];
#pragma unroll
    for (int i = 0; i < 2; ++i)
#pragma unroll
      for (int j = 0; j < 8; ++j) hacc[i][j] = (f32x4)0.f;
#pragma unroll
    for (int kc = 0; kc < 4; ++kc) {
      bf16x8 av0 = *(const bf16x8*)&a_lds[ml * 136 + kc * 32 + 8 * gq];
      bf16x8 av1 = *(const bf16x8*)&a_lds[(ml + 16) * 136 + kc * 32 + 8 * gq];
#pragma unroll
      for (int nf = 0; nf < 8; ++nf) {
        int h = 128 * w + 16 * nf + ml;
        bf16x8 bv = *(const bf16x8*)&Wm1bf[h * 128 + kc * 32 + 8 * gq];
        hacc[0][nf] = __builtin_amdgcn_mfma_f32_16x16x32_bf16(av0, bv, hacc[0][nf], 0, 0, 0);
        hacc[1][nf] = __builtin_amdgcn_mfma_f32_16x16x32_bf16(av1, bv, hacc[1][nf], 0, 0, 0);
      }
    }
#pragma unroll
    for (int mf = 0; mf < 2; ++mf)
#pragma unroll
      for (int nf = 0; nf < 8; ++nf) {
        int h = 128 * w + 16 * nf + ml;
        float bias = bm1[h];
#pragma unroll
        for (int r = 0; r < 4; ++r)
          h_lds[(16 * mf + 4 * gq + r) * 520 + h] = f2bf(fmaxf(hacc[mf][nf][r] + bias, 0.f));
      }
  }
  __syncthreads();
  // layer2: wave w -> co cols [32w, 32w+32)
  {
    f32x4 oacc[2][2];
#pragma unroll
    for (int i = 0; i < 2; ++i)
#pragma unroll
      for (int j = 0; j < 2; ++j) oacc[i][j] = (f32x4)0.f;
#pragma unroll
    for (int kc = 0; kc < 16; ++kc) {
      bf16x8 av0 = *(const bf16x8*)&h_lds[ml * 520 + kc * 32 + 8 * gq];
      bf16x8 av1 = *(const bf16x8*)&h_lds[(ml + 16) * 520 + kc * 32 + 8 * gq];
#pragma unroll
      for (int nf = 0; nf < 2; ++nf) {
        int co = 32 * w + 16 * nf + ml;
        bf16x8 bv = *(const bf16x8*)&Wm2bf[co * 512 + kc * 32 + 8 * gq];
        oacc[0][nf] = __builtin_amdgcn_mfma_f32_16x16x32_bf16(av0, bv, oacc[0][nf], 0, 0, 0);
        oacc[1][nf] = __builtin_amdgcn_mfma_f32_16x16x32_bf16(av1, bv, oacc[1][nf], 0, 0, 0);
      }
    }
#pragma unroll
    for (int mf = 0; mf < 2; ++mf)
#pragma unroll
      for (int nf = 0; nf < 2; ++nf) {
        int co = 32 * w + 16 * nf + ml;
        float bias = bm2[co];
#pragma unroll
        for (int r = 0; r < 4; ++r)
          out_s[co * 33 + 16 * mf + 4 * gq + r] = oacc[mf][nf][r] + bias;
      }
  }
  __syncthreads();
#pragma unroll
  for (int i = 0; i < 16; ++i) {
    int id = t + 256 * i;
    int co = id >> 5, j = id & 31;
    out[(b * Cn + co) * Nn + n0 + j] = out_s[co * 33 + j] + x[(b * Cn + co) * Nn + n0 + j];
  }
}

extern "C" void kernel_launch(void* const* d_in, const int* in_sizes, int n_in,
                              void* d_out, int out_size, void* d_ws, size_t ws_size,
                              hipStream_t stream) {
  const float* pos  = (const float*)d_in[0];
  const float* x    = (const float*)d_in[1];
  const int*   idx  = (const int*)d_in[2];
  const float* dist = (const float*)d_in[3];
  const float* Wqkv = (const float*)d_in[4];
  const float* W1   = (const float*)d_in[5];
  const float* b1   = (const float*)d_in[6];
  const float* W2   = (const float*)d_in[7];
  const float* b2   = (const float*)d_in[8];
  const float* Wm1  = (const float*)d_in[9];
  const float* bm1  = (const float*)d_in[10];
  const float* Wm2  = (const float*)d_in[11];
  const float* bm2  = (const float*)d_in[12];
  float* out = (float*)d_out;
  float* ws = (float*)d_ws;

  hipMemsetAsync(ws + OFF_KVT32, 0, (size_t)Bn * Kn * Cn * Cn * sizeof(float), stream);
  hipLaunchKernelGGL(k0_prep, dim3(736), dim3(256), 0, stream, Wqkv, Wm1, Wm2, W2, idx, ws);
  hipLaunchKernelGGL(k1_qkv, dim3(Bn * 128), dim3(256), 0, stream, x, ws);
  hipLaunchKernelGGL(k2_kv, dim3(Bn * Kn * CH2), dim3(256), 0, stream, pos, dist, idx, W1, b1, b2, ws);
  hipLaunchKernelGGL(k2b_cvt, dim3(512), dim3(256), 0, stream, ws);
  hipLaunchKernelGGL(k3_agg, dim3(Bn * 2 * 128), dim3(256), 0, stream, idx, ws);
  hipLaunchKernelGGL(k4_mlp, dim3(Bn * 128), dim3(256), 0, stream, x, bm1, bm2, out, ws);
}